// Round 5
// baseline (3282.388 us; speedup 1.0000x reference)
//
#include <hip/hip_runtime.h>
#include <hip/hip_bf16.h>
#include <cstddef>

#define HID 128
#define EMBD 32
#define NIN 32
#define EIN 16
#define EPSV 1e-5f

__device__ __forceinline__ float rlf(float v, int l) {
    return __int_as_float(__builtin_amdgcn_readlane(__float_as_int(v), l));
}

// ---------------- embedding + layernorm + input projection ----------------
extern "C" __global__ void __launch_bounds__(256)
k_input(const float* __restrict__ x, const float* __restrict__ etab,
        const int* __restrict__ nidx, const float* __restrict__ lng_,
        const float* __restrict__ lnb_, const float* __restrict__ Win,
        const float* __restrict__ bin_, float* __restrict__ h,
        float* __restrict__ init_, int nn)
{
    __shared__ float Ws[64 * HID];           // 32KB
    __shared__ float lng[EMBD], lnb[EMBD], bin[HID];
    __shared__ float xbuf[4][64];
    for (int i = threadIdx.x; i < 64 * HID; i += 256) Ws[i] = Win[i];
    if (threadIdx.x < EMBD) { lng[threadIdx.x] = lng_[threadIdx.x]; lnb[threadIdx.x] = lnb_[threadIdx.x]; }
    if (threadIdx.x < HID) bin[threadIdx.x] = bin_[threadIdx.x];
    __syncthreads();
    const int wv = threadIdx.x >> 6, lane = threadIdx.x & 63;
    const int w0 = blockIdx.x * 4 + wv, nw = gridDim.x * 4;
    for (int n = w0; n < nn; n += nw) {
        float e = 0.f;
        if (lane < EMBD) e = etab[(size_t)nidx[n] * EMBD + lane];
        float s = e, q = e * e;
        #pragma unroll
        for (int o = 16; o; o >>= 1) { s += __shfl_xor(s, o, 32); q += __shfl_xor(q, o, 32); }
        if (lane < EMBD) {
            float m = s * (1.f / EMBD);
            float v = q * (1.f / EMBD) - m * m;
            xbuf[wv][lane] = (e - m) * rsqrtf(v + EPSV) * lng[lane] + lnb[lane];
        } else {
            xbuf[wv][lane] = x[(size_t)n * NIN + (lane - NIN)];
        }
        float2 a0 = *(const float2*)&bin[2 * lane], a1 = {0.f, 0.f};
        #pragma unroll 8
        for (int k = 0; k < 64; k += 2) {
            float2 wA = *(const float2*)&Ws[k * HID + 2 * lane];
            float2 wB = *(const float2*)&Ws[(k + 1) * HID + 2 * lane];
            a0.x = fmaf(xbuf[wv][k], wA.x, a0.x);     a0.y = fmaf(xbuf[wv][k], wA.y, a0.y);
            a1.x = fmaf(xbuf[wv][k + 1], wB.x, a1.x); a1.y = fmaf(xbuf[wv][k + 1], wB.y, a1.y);
        }
        float2 r; r.x = fmaxf(a0.x + a1.x, 0.f); r.y = fmaxf(a0.y + a1.y, 0.f);
        *(float2*)&h[(size_t)n * HID + 2 * lane] = r;
        *(float2*)&init_[(size_t)n * HID + 2 * lane] = r;
    }
}

// ---------------- CSR build: degree, scan, fill ----------------
extern "C" __global__ void k_deg(const int* __restrict__ col, int* __restrict__ degi, int ne) {
    int i = blockIdx.x * blockDim.x + threadIdx.x, st = gridDim.x * blockDim.x;
    for (; i < ne; i += st) atomicAdd(&degi[col[i]], 1);
}

extern "C" __global__ void __launch_bounds__(1024)
k_scan(const int* __restrict__ degi, int* __restrict__ offs, int nn) {
    __shared__ int ps[1024];
    const int t = threadIdx.x;
    const int per = (nn + 1023) / 1024;
    const int s = min(t * per, nn), e = min(s + per, nn);
    int sum = 0;
    for (int i = s; i < e; i++) sum += degi[i];
    ps[t] = sum;
    __syncthreads();
    for (int off = 1; off < 1024; off <<= 1) {
        int v = (t >= off) ? ps[t - off] : 0;
        __syncthreads();
        ps[t] += v;
        __syncthreads();
    }
    int run = (t ? ps[t - 1] : 0);
    for (int i = s; i < e; i++) { offs[i] = run; run += degi[i]; }
    if (t == 1023) offs[nn] = run;
}

extern "C" __global__ void k_fill(const int* __restrict__ row, const int* __restrict__ col,
                                  const int* __restrict__ offs, int* __restrict__ cur,
                                  int* __restrict__ csr, int ne) {
    int i = blockIdx.x * blockDim.x + threadIdx.x, st = gridDim.x * blockDim.x;
    for (; i < ne; i += st) {
        int c = col[i];
        int p = atomicAdd(&cur[c], 1);
        csr[offs[c] + p] = row[i];
    }
}

// ---------------- CSR aggregation: agg[n] = mean_{j in in(n)} h[j] ----------------
// 8-deep index prefetch -> 8 outstanding row gathers per wave.
extern "C" __global__ void __launch_bounds__(256)
k_agg(const float* __restrict__ h, const int* __restrict__ offs,
      const int* __restrict__ csr, float* __restrict__ agg, int nn)
{
    const int lane = threadIdx.x & 63;
    int w = blockIdx.x * 4 + (threadIdx.x >> 6), nw = gridDim.x * 4;
    for (int n = w; n < nn; n += nw) {
        const int o0 = offs[n], o1 = offs[n + 1];
        float2 acc0 = {0.f, 0.f}, acc1 = {0.f, 0.f};
        int j = o0;
        for (; j + 8 <= o1; j += 8) {
            int s[8];
            #pragma unroll
            for (int i = 0; i < 8; i++) s[i] = csr[j + i];
            float2 v[8];
            #pragma unroll
            for (int i = 0; i < 8; i++) v[i] = *(const float2*)&h[(size_t)s[i] * HID + 2 * lane];
            #pragma unroll
            for (int i = 0; i < 8; i += 2) {
                acc0.x += v[i].x;     acc0.y += v[i].y;
                acc1.x += v[i + 1].x; acc1.y += v[i + 1].y;
            }
        }
        for (; j < o1; j++) {
            int s0 = csr[j];
            float2 v0 = *(const float2*)&h[(size_t)s0 * HID + 2 * lane];
            acc0.x += v0.x; acc0.y += v0.y;
        }
        const float idg = 1.f / fmaxf((float)(o1 - o0), 1.f);
        float2 r; r.x = (acc0.x + acc1.x) * idg; r.y = (acc0.y + acc1.y) * idg;
        *(float2*)&agg[(size_t)n * HID + 2 * lane] = r;
    }
}

// ---------------- atomic-scatter fallback path ----------------
extern "C" __global__ void k_degf(const int* __restrict__ col, float* __restrict__ deg, int ne) {
    int i = blockIdx.x * blockDim.x + threadIdx.x, st = gridDim.x * blockDim.x;
    for (; i < ne; i += st) unsafeAtomicAdd(&deg[col[i]], 1.f);
}
extern "C" __global__ void k_invdeg(const float* __restrict__ deg, float* __restrict__ inv, int nn) {
    int i = blockIdx.x * blockDim.x + threadIdx.x;
    if (i < nn) inv[i] = 1.f / fmaxf(deg[i], 1.f);
}
extern "C" __global__ void __launch_bounds__(256)
k_scatter(const float* __restrict__ h, const int* __restrict__ row,
          const int* __restrict__ col, float* agg, int ne)
{
    const int lane = threadIdx.x & 63;
    int w = blockIdx.x * 4 + (threadIdx.x >> 6), nw = gridDim.x * 4;
    for (int e = w; e < ne; e += nw) {
        int r = row[e], c = col[e];
        float2 v = *(const float2*)&h[(size_t)r * HID + 2 * lane];
        unsafeAtomicAdd(&agg[(size_t)c * HID + 2 * lane], v.x);
        unsafeAtomicAdd(&agg[(size_t)c * HID + 2 * lane + 1], v.y);
    }
}

// ---------------- node GEMM: out = (X1*scale)@W1 [+ X2@W2] + bias, optional BN stats ----
// 1024 threads (16 waves) -> 4 waves/SIMD at 1 block/CU (128KB LDS).
extern "C" __global__ void __launch_bounds__(1024)
k_gemm(const float* __restrict__ X1, const float* __restrict__ scale,
       const float* __restrict__ W1, const float* __restrict__ X2,
       const float* __restrict__ W2, const float* __restrict__ bias,
       float* __restrict__ out, float* __restrict__ stats, int nn)
{
    __shared__ float W1s[HID * HID];   // 64KB
    __shared__ float W2s[HID * HID];   // 64KB
    const int tid = threadIdx.x;
    const bool dual = (X2 != nullptr);
    for (int i = tid; i < HID * HID / 4; i += 1024) {
        ((float4*)W1s)[i] = ((const float4*)W1)[i];
        if (dual) ((float4*)W2s)[i] = ((const float4*)W2)[i];
    }
    __syncthreads();
    const int lane = tid & 63, wv = tid >> 6;          // wv in [0,16)
    const int gw = blockIdx.x * 16 + wv, nwv = gridDim.x * 16;
    float2 bv = {0.f, 0.f};
    if (bias) bv = *(const float2*)&bias[2 * lane];
    float2 sm = {0.f, 0.f}, sq = {0.f, 0.f};
    for (int nb = gw * 8; nb < nn; nb += nwv * 8) {
        const int nN = min(8, nn - nb);
        float2 xA[8], xB[8];
        #pragma unroll
        for (int i = 0; i < 8; i++) {
            xA[i] = {0.f, 0.f}; xB[i] = {0.f, 0.f};
            if (i < nN) {
                xA[i] = *(const float2*)&X1[(size_t)(nb + i) * HID + 2 * lane];
                if (scale) { float sc = scale[nb + i]; xA[i].x *= sc; xA[i].y *= sc; }
                if (dual) xB[i] = *(const float2*)&X2[(size_t)(nb + i) * HID + 2 * lane];
            }
        }
        float2 acc[8];
        #pragma unroll
        for (int i = 0; i < 8; i++) acc[i] = bv;
        if (dual) {
            for (int k = 0; k < HID; k += 2) {
                float2 w1a = *(const float2*)&W1s[k * HID + 2 * lane];
                float2 w1b = *(const float2*)&W1s[(k + 1) * HID + 2 * lane];
                float2 w2a = *(const float2*)&W2s[k * HID + 2 * lane];
                float2 w2b = *(const float2*)&W2s[(k + 1) * HID + 2 * lane];
                const int kl = k >> 1;
                #pragma unroll
                for (int i = 0; i < 8; i++) {
                    float sa = rlf(xA[i].x, kl), sb = rlf(xA[i].y, kl);
                    float ta = rlf(xB[i].x, kl), tb = rlf(xB[i].y, kl);
                    acc[i].x = fmaf(sa, w1a.x, acc[i].x); acc[i].y = fmaf(sa, w1a.y, acc[i].y);
                    acc[i].x = fmaf(sb, w1b.x, acc[i].x); acc[i].y = fmaf(sb, w1b.y, acc[i].y);
                    acc[i].x = fmaf(ta, w2a.x, acc[i].x); acc[i].y = fmaf(ta, w2a.y, acc[i].y);
                    acc[i].x = fmaf(tb, w2b.x, acc[i].x); acc[i].y = fmaf(tb, w2b.y, acc[i].y);
                }
            }
        } else {
            for (int k = 0; k < HID; k += 2) {
                float2 w1a = *(const float2*)&W1s[k * HID + 2 * lane];
                float2 w1b = *(const float2*)&W1s[(k + 1) * HID + 2 * lane];
                const int kl = k >> 1;
                #pragma unroll
                for (int i = 0; i < 8; i++) {
                    float sa = rlf(xA[i].x, kl), sb = rlf(xA[i].y, kl);
                    acc[i].x = fmaf(sa, w1a.x, acc[i].x); acc[i].y = fmaf(sa, w1a.y, acc[i].y);
                    acc[i].x = fmaf(sb, w1b.x, acc[i].x); acc[i].y = fmaf(sb, w1b.y, acc[i].y);
                }
            }
        }
        #pragma unroll
        for (int i = 0; i < 8; i++) {
            if (i < nN) {
                *(float2*)&out[(size_t)(nb + i) * HID + 2 * lane] = acc[i];
                if (stats) {
                    sm.x += acc[i].x; sm.y += acc[i].y;
                    sq.x += acc[i].x * acc[i].x; sq.y += acc[i].y * acc[i].y;
                }
            }
        }
    }
    if (stats) {
        unsafeAtomicAdd(&stats[2 * lane],           sm.x);
        unsafeAtomicAdd(&stats[2 * lane + 1],       sm.y);
        unsafeAtomicAdd(&stats[HID + 2 * lane],     sq.x);
        unsafeAtomicAdd(&stats[HID + 2 * lane + 1], sq.y);
    }
}

// ---------------- BN finalize ----------------
extern "C" __global__ void k_bnfin(const float* __restrict__ stats, const float* __restrict__ g,
                                   const float* __restrict__ b, float* __restrict__ scsh, float invn)
{
    int f = threadIdx.x;
    if (f < HID) {
        float m = stats[f] * invn;
        float v = stats[HID + f] * invn - m * m;
        float s = rsqrtf(v + EPSV) * g[f];
        scsh[f] = s;
        scsh[HID + f] = fmaf(-m, s, b[f]);
    }
}

// ---------------- h = tanh(out*sc+sh) + h (+ initial) ----------------
extern "C" __global__ void __launch_bounds__(256)
k_update(const float* __restrict__ outb, const float* __restrict__ scsh,
         float* h, const float* __restrict__ init_, int addinit, int n4)
{
    int i = blockIdx.x * blockDim.x + threadIdx.x, st = gridDim.x * blockDim.x;
    for (; i < n4; i += st) {
        float4 o = ((const float4*)outb)[i];
        int f = (i & 31) * 4;
        float4 s  = *(const float4*)&scsh[f];
        float4 sh = *(const float4*)&scsh[HID + f];
        float4 hv = ((const float4*)h)[i];
        float4 r;
        r.x = tanhf(fmaf(o.x, s.x, sh.x)) + hv.x;
        r.y = tanhf(fmaf(o.y, s.y, sh.y)) + hv.y;
        r.z = tanhf(fmaf(o.z, s.z, sh.z)) + hv.z;
        r.w = tanhf(fmaf(o.w, s.w, sh.w)) + hv.w;
        if (addinit) {
            float4 iv = ((const float4*)init_)[i];
            r.x += iv.x; r.y += iv.y; r.z += iv.z; r.w += iv.w;
        }
        ((float4*)h)[i] = r;
    }
}

// ---------------- fused edge MLP (software-pipelined) ----------------
// chunk = 32 edges/block-iter. Prefetch of chunk t+1's row/col/ea/A/B issues
// between phase A and phase B of chunk t, hiding gather latency under FMAs.
extern "C" __global__ void __launch_bounds__(256)
k_edge(const float* __restrict__ A, const float* __restrict__ B,
       const float* __restrict__ eattr, const int* __restrict__ row,
       const int* __restrict__ col, const float* __restrict__ We1e,
       const float* __restrict__ We2, const float* __restrict__ be2,
       const float* __restrict__ We3, const float* __restrict__ be3,
       float* __restrict__ outp, int ne)
{
    __shared__ float zbuf[32][132];     // swizzled z
    __shared__ float tbuf[4][32][8];    // per-wave partial edge sums
    const int tid = threadIdx.x, lane = tid & 63, wv = tid >> 6;
    float2 w1r[16];
    #pragma unroll
    for (int j = 0; j < 16; j++) w1r[j] = *(const float2*)&We1e[j * HID + 2 * lane];
    const int fi = lane & 7, ks = lane >> 3;
    const int f0 = 16 * wv + 2 * fi;
    float w2r0[16], w2r1[16];
    #pragma unroll
    for (int m = 0; m < 16; m++) {
        w2r0[m] = We2[(16 * ks + m) * 64 + f0];
        w2r1[m] = We2[(16 * ks + m) * 64 + f0 + 1];
    }
    const float b20 = be2[f0], b21 = be2[f0 + 1];
    const float w30 = We3[f0], w31 = We3[f0 + 1];
    const float bias3 = be3[0];
    const int wcol4 = (((lane >> 1) & 3) << 3) | ((lane >> 1) >> 2);
    const int woff = wcol4 * 4 + (lane & 1) * 2;
    const int stride = gridDim.x * 32;

    // prefetch registers (live across phase B)
    float2 ear, av[8], bv8[8];

#define PREF(cbase)                                                            \
    {                                                                          \
        const int e0p = (cbase) + wv * 8;                                      \
        ear = make_float2(0.f, 0.f);                                           \
        if (e0p + (lane >> 3) < ne)                                            \
            ear = *(const float2*)&eattr[(size_t)e0p * EIN + 2 * lane];        \
        _Pragma("unroll")                                                      \
        for (int i = 0; i < 8; i++) {                                          \
            const int e = e0p + i;                                             \
            const int r = (e < ne) ? row[e] : 0;                               \
            const int c = (e < ne) ? col[e] : 0;                               \
            av[i]  = *(const float2*)&A[(size_t)r * HID + 2 * lane];           \
            bv8[i] = *(const float2*)&B[(size_t)c * HID + 2 * lane];           \
        }                                                                      \
    }

    int cb = blockIdx.x * 32;
    if (cb < ne) PREF(cb);
    for (; cb < ne; cb += stride) {
        // ---- phase A: compute z from prefetched regs ----
        #pragma unroll
        for (int i = 0; i < 8; i++) {
            float2 q; q.x = av[i].x + bv8[i].x; q.y = av[i].y + bv8[i].y;
            #pragma unroll
            for (int j = 0; j < 16; j++) {
                float s = rlf((j & 1) ? ear.y : ear.x, i * 8 + (j >> 1));
                q.x = fmaf(s, w1r[j].x, q.x);
                q.y = fmaf(s, w1r[j].y, q.y);
            }
            q.x = fmaxf(q.x, 0.f); q.y = fmaxf(q.y, 0.f);
            *(float2*)&zbuf[wv * 8 + i][woff] = q;
        }
        __syncthreads();                       // z visible to all waves
        // ---- prefetch next chunk (VMEM in flight under phase B) ----
        if (cb + stride < ne) PREF(cb + stride);
        // ---- phase B ----
        for (int e = 0; e < 32; e++) {
            float acc0 = 0.f, acc1 = 0.f;
            #pragma unroll
            for (int t = 0; t < 4; t++) {
                float4 z = *(const float4*)&zbuf[e][(t * 8 + ks) * 4];
                acc0 = fmaf(z.x, w2r0[4 * t + 0], acc0);
                acc0 = fmaf(z.y, w2r0[4 * t + 1], acc0);
                acc0 = fmaf(z.z, w2r0[4 * t + 2], acc0);
                acc0 = fmaf(z.w, w2r0[4 * t + 3], acc0);
                acc1 = fmaf(z.x, w2r1[4 * t + 0], acc1);
                acc1 = fmaf(z.y, w2r1[4 * t + 1], acc1);
                acc1 = fmaf(z.z, w2r1[4 * t + 2], acc1);
                acc1 = fmaf(z.w, w2r1[4 * t + 3], acc1);
            }
            acc0 += __shfl_xor(acc0, 8);  acc1 += __shfl_xor(acc1, 8);
            acc0 += __shfl_xor(acc0, 16); acc1 += __shfl_xor(acc1, 16);
            acc0 += __shfl_xor(acc0, 32); acc1 += __shfl_xor(acc1, 32);
            float o0 = fmaxf(acc0 + b20, 0.f), o1 = fmaxf(acc1 + b21, 0.f);
            float t3 = fmaf(o0, w30, o1 * w31);
            if (ks == 0) tbuf[wv][e][fi] = t3;
        }
        __syncthreads();                       // tbuf ready; zbuf reads done
        {
            const int e = tid >> 3, p = tid & 7;
            float s = (tbuf[0][e][p] + tbuf[1][e][p]) + (tbuf[2][e][p] + tbuf[3][e][p]);
            s += __shfl_xor(s, 1); s += __shfl_xor(s, 2); s += __shfl_xor(s, 4);
            if (p == 0 && cb + e < ne) outp[cb + e] = s + bias3;
        }
        __syncthreads();                       // tbuf reads done
    }
#undef PREF
}

extern "C" void kernel_launch(void* const* d_in, const int* in_sizes, int n_in,
                              void* d_out, int out_size, void* d_ws, size_t ws_size,
                              hipStream_t stream)
{
    const float* x     = (const float*)d_in[0];
    const float* eattr = (const float*)d_in[1];
    const float* etab  = (const float*)d_in[2];
    const float* lng   = (const float*)d_in[3];
    const float* lnb   = (const float*)d_in[4];
    const float* Win   = (const float*)d_in[5];
    const float* bin   = (const float*)d_in[6];
    const float* Wl    = (const float*)d_in[7];
    const float* bl    = (const float*)d_in[8];
    const float* Wr    = (const float*)d_in[9];
    const float* bng   = (const float*)d_in[10];
    const float* bnb   = (const float*)d_in[11];
    const float* We1   = (const float*)d_in[12];
    const float* be1   = (const float*)d_in[13];
    const float* We2   = (const float*)d_in[14];
    const float* be2   = (const float*)d_in[15];
    const float* We3   = (const float*)d_in[16];
    const float* be3   = (const float*)d_in[17];
    const int*   eidx  = (const int*)d_in[18];
    const int*   nidx  = (const int*)d_in[19];

    const int nn = in_sizes[0] / NIN;     // 100000
    const int ne = in_sizes[1] / EIN;     // 1600000
    const int* row = eidx;
    const int* col = eidx + ne;

    float* ws = (float*)d_ws;
    const size_t big = (size_t)nn * HID;
    float* h    = ws;                 // N*128
    float* bufB = ws + big;           // N*128  (initial; later B-projection)
    float* bufA = ws + 2 * big;       // N*128  (agg / gemm-out; later A-projection)
    float* tail = ws + 3 * big;

    const size_t need_csr = (3 * big + 3 * (size_t)nn + 1 + (size_t)ne + 512) * 4;
    const bool use_csr = (ws_size >= need_csr);

    k_input<<<512, 256, 0, stream>>>(x, etab, nidx, lng, lnb, Win, bin, h, bufB, nn);

    if (use_csr) {
        int*   degi  = (int*)tail;                  // N
        int*   offs  = degi + nn;                   // N+1
        int*   cur   = offs + nn + 1;               // N
        int*   csr   = cur + nn;                    // E
        float* stats = (float*)(csr + ne);          // 256
        float* scsh  = stats + 2 * HID;             // 256

        hipMemsetAsync(degi, 0, (size_t)nn * 4, stream);
        hipMemsetAsync(cur, 0, (size_t)nn * 4, stream);
        k_deg<<<1024, 256, 0, stream>>>(col, degi, ne);
        k_scan<<<1, 1024, 0, stream>>>(degi, offs, nn);
        k_fill<<<1024, 256, 0, stream>>>(row, col, offs, cur, csr, ne);

        for (int i = 0; i < 3; i++) {
            hipMemsetAsync(stats, 0, 2 * HID * 4, stream);
            k_agg<<<6400, 256, 0, stream>>>(h, offs, csr, bufA, nn);
            k_gemm<<<256, 1024, 0, stream>>>(bufA, nullptr, Wl + (size_t)i * HID * HID,
                                             h, Wr + (size_t)i * HID * HID, bl + i * HID,
                                             bufA, stats, nn);
            k_bnfin<<<1, 128, 0, stream>>>(stats, bng + i * HID, bnb + i * HID, scsh, 1.0f / nn);
            k_update<<<1024, 256, 0, stream>>>(bufA, scsh, h, bufB, i & 1, nn * HID / 4);
        }

        k_gemm<<<256, 1024, 0, stream>>>(h, nullptr, We1, nullptr, nullptr, be1, bufA, nullptr, nn);
        k_gemm<<<256, 1024, 0, stream>>>(h, nullptr, We1 + HID * HID, nullptr, nullptr, nullptr, bufB, nullptr, nn);
    } else {
        // atomic-scatter fallback (smaller workspace footprint)
        float* deg   = tail;                        // N
        float* inv   = deg + nn;                    // N
        float* stats = inv + nn;                    // 256
        float* scsh  = stats + 2 * HID;             // 256

        hipMemsetAsync(deg, 0, (size_t)nn * 4, stream);
        k_degf<<<1024, 256, 0, stream>>>(col, deg, ne);
        k_invdeg<<<(nn + 255) / 256, 256, 0, stream>>>(deg, inv, nn);

        for (int i = 0; i < 3; i++) {
            hipMemsetAsync(bufA, 0, big * 4, stream);
            hipMemsetAsync(stats, 0, 2 * HID * 4, stream);
            k_scatter<<<2048, 256, 0, stream>>>(h, row, col, bufA, ne);
            k_gemm<<<256, 1024, 0, stream>>>(bufA, inv, Wl + (size_t)i * HID * HID,
                                             h, Wr + (size_t)i * HID * HID, bl + i * HID,
                                             bufA, stats, nn);
            k_bnfin<<<1, 128, 0, stream>>>(stats, bng + i * HID, bnb + i * HID, scsh, 1.0f / nn);
            k_update<<<1024, 256, 0, stream>>>(bufA, scsh, h, bufB, i & 1, nn * HID / 4);
        }

        k_gemm<<<256, 1024, 0, stream>>>(h, nullptr, We1, nullptr, nullptr, be1, bufA, nullptr, nn);
        k_gemm<<<256, 1024, 0, stream>>>(h, nullptr, We1 + HID * HID, nullptr, nullptr, nullptr, bufB, nullptr, nn);
    }

    k_edge<<<2560, 256, 0, stream>>>(bufA, bufB, eattr, row, col,
                                     We1 + 2 * HID * HID, We2, be2, We3, be3,
                                     (float*)d_out, ne);
}

// Round 9
// 2896.580 us; speedup vs baseline: 1.1332x; 1.1332x over previous
//
#include <hip/hip_runtime.h>
#include <hip/hip_bf16.h>
#include <cstddef>

#define HID 128
#define EMBD 32
#define NIN 32
#define EIN 16
#define EPSV 1e-5f

__device__ __forceinline__ float rlf(float v, int l) {
    return __int_as_float(__builtin_amdgcn_readlane(__float_as_int(v), l));
}

// ---------------- embedding + layernorm + input projection (+ zero degi/cur) ----------------
extern "C" __global__ void __launch_bounds__(256)
k_input(const float* __restrict__ x, const float* __restrict__ etab,
        const int* __restrict__ nidx, const float* __restrict__ lng_,
        const float* __restrict__ lnb_, const float* __restrict__ Win,
        const float* __restrict__ bin_, float* __restrict__ h,
        float* __restrict__ init_, int* __restrict__ zi, int* __restrict__ zc, int nn)
{
    __shared__ float Ws[64 * HID];           // 32KB
    __shared__ float lng[EMBD], lnb[EMBD], bin[HID];
    __shared__ float xbuf[4][64];
    if (zi) {
        int gid = blockIdx.x * blockDim.x + threadIdx.x, st = gridDim.x * blockDim.x;
        for (int i = gid; i < nn; i += st) { zi[i] = 0; zc[i] = 0; }
    }
    for (int i = threadIdx.x; i < 64 * HID; i += 256) Ws[i] = Win[i];
    if (threadIdx.x < EMBD) { lng[threadIdx.x] = lng_[threadIdx.x]; lnb[threadIdx.x] = lnb_[threadIdx.x]; }
    if (threadIdx.x < HID) bin[threadIdx.x] = bin_[threadIdx.x];
    __syncthreads();
    const int wv = threadIdx.x >> 6, lane = threadIdx.x & 63;
    const int w0 = blockIdx.x * 4 + wv, nw = gridDim.x * 4;
    for (int n = w0; n < nn; n += nw) {
        float e = 0.f;
        if (lane < EMBD) e = etab[(size_t)nidx[n] * EMBD + lane];
        float s = e, q = e * e;
        #pragma unroll
        for (int o = 16; o; o >>= 1) { s += __shfl_xor(s, o, 32); q += __shfl_xor(q, o, 32); }
        if (lane < EMBD) {
            float m = s * (1.f / EMBD);
            float v = q * (1.f / EMBD) - m * m;
            xbuf[wv][lane] = (e - m) * rsqrtf(v + EPSV) * lng[lane] + lnb[lane];
        } else {
            xbuf[wv][lane] = x[(size_t)n * NIN + (lane - NIN)];
        }
        float2 a0 = *(const float2*)&bin[2 * lane], a1 = {0.f, 0.f};
        #pragma unroll 8
        for (int k = 0; k < 64; k += 2) {
            float2 wA = *(const float2*)&Ws[k * HID + 2 * lane];
            float2 wB = *(const float2*)&Ws[(k + 1) * HID + 2 * lane];
            a0.x = fmaf(xbuf[wv][k], wA.x, a0.x);     a0.y = fmaf(xbuf[wv][k], wA.y, a0.y);
            a1.x = fmaf(xbuf[wv][k + 1], wB.x, a1.x); a1.y = fmaf(xbuf[wv][k + 1], wB.y, a1.y);
        }
        float2 r; r.x = fmaxf(a0.x + a1.x, 0.f); r.y = fmaxf(a0.y + a1.y, 0.f);
        *(float2*)&h[(size_t)n * HID + 2 * lane] = r;
        *(float2*)&init_[(size_t)n * HID + 2 * lane] = r;
    }
}

// ---------------- CSR build ----------------
extern "C" __global__ void k_deg(const int* __restrict__ col, int* __restrict__ degi, int ne) {
    int i = blockIdx.x * blockDim.x + threadIdx.x, st = gridDim.x * blockDim.x;
    for (; i < ne; i += st) atomicAdd(&degi[col[i]], 1);
}

extern "C" __global__ void __launch_bounds__(1024)
k_scan(const int* __restrict__ degi, int* __restrict__ offs, int nn) {
    __shared__ int ps[1024];
    const int t = threadIdx.x;
    const int per = (nn + 1023) / 1024;
    const int s = min(t * per, nn), e = min(s + per, nn);
    int sum = 0;
    for (int i = s; i < e; i++) sum += degi[i];
    ps[t] = sum;
    __syncthreads();
    for (int off = 1; off < 1024; off <<= 1) {
        int v = (t >= off) ? ps[t - off] : 0;
        __syncthreads();
        ps[t] += v;
        __syncthreads();
    }
    int run = (t ? ps[t - 1] : 0);
    for (int i = s; i < e; i++) { offs[i] = run; run += degi[i]; }
    if (t == 1023) offs[nn] = run;
}

extern "C" __global__ void k_fill(const int* __restrict__ row, const int* __restrict__ col,
                                  const int* __restrict__ offs, int* __restrict__ cur,
                                  int* __restrict__ csr, int ne) {
    int i = blockIdx.x * blockDim.x + threadIdx.x, st = gridDim.x * blockDim.x;
    for (; i < ne; i += st) {
        int c = col[i];
        int p = atomicAdd(&cur[c], 1);
        csr[offs[c] + p] = row[i];
    }
}

// ---------------- CSR aggregation (+ zero stats for next gemm) ----------------
extern "C" __global__ void __launch_bounds__(256)
k_agg(const float* __restrict__ h, const int* __restrict__ offs,
      const int* __restrict__ csr, float* __restrict__ agg,
      float* __restrict__ stats, int nn)
{
    if (blockIdx.x == 0 && threadIdx.x < 2 * HID) stats[threadIdx.x] = 0.f;
    const int lane = threadIdx.x & 63;
    int w = blockIdx.x * 4 + (threadIdx.x >> 6), nw = gridDim.x * 4;
    for (int n = w; n < nn; n += nw) {
        const int o0 = offs[n], o1 = offs[n + 1];
        float2 acc0 = {0.f, 0.f}, acc1 = {0.f, 0.f};
        int j = o0;
        for (; j + 8 <= o1; j += 8) {
            int s[8];
            #pragma unroll
            for (int i = 0; i < 8; i++) s[i] = csr[j + i];
            float2 v[8];
            #pragma unroll
            for (int i = 0; i < 8; i++) v[i] = *(const float2*)&h[(size_t)s[i] * HID + 2 * lane];
            #pragma unroll
            for (int i = 0; i < 8; i += 2) {
                acc0.x += v[i].x;     acc0.y += v[i].y;
                acc1.x += v[i + 1].x; acc1.y += v[i + 1].y;
            }
        }
        for (; j < o1; j++) {
            int s0 = csr[j];
            float2 v0 = *(const float2*)&h[(size_t)s0 * HID + 2 * lane];
            acc0.x += v0.x; acc0.y += v0.y;
        }
        const float idg = 1.f / fmaxf((float)(o1 - o0), 1.f);
        float2 r; r.x = (acc0.x + acc1.x) * idg; r.y = (acc0.y + acc1.y) * idg;
        *(float2*)&agg[(size_t)n * HID + 2 * lane] = r;
    }
}

// ---------------- atomic-scatter fallback path ----------------
extern "C" __global__ void k_degf(const int* __restrict__ col, float* __restrict__ deg, int ne) {
    int i = blockIdx.x * blockDim.x + threadIdx.x, st = gridDim.x * blockDim.x;
    for (; i < ne; i += st) unsafeAtomicAdd(&deg[col[i]], 1.f);
}
extern "C" __global__ void k_invdeg(const float* __restrict__ deg, float* __restrict__ inv, int nn) {
    int i = blockIdx.x * blockDim.x + threadIdx.x;
    if (i < nn) inv[i] = 1.f / fmaxf(deg[i], 1.f);
}
extern "C" __global__ void __launch_bounds__(256)
k_scatter(const float* __restrict__ h, const int* __restrict__ row,
          const int* __restrict__ col, float* agg, float* __restrict__ stats, int ne)
{
    if (blockIdx.x == 0 && threadIdx.x < 2 * HID) stats[threadIdx.x] = 0.f;
    const int lane = threadIdx.x & 63;
    int w = blockIdx.x * 4 + (threadIdx.x >> 6), nw = gridDim.x * 4;
    for (int e = w; e < ne; e += nw) {
        int r = row[e], c = col[e];
        float2 v = *(const float2*)&h[(size_t)r * HID + 2 * lane];
        unsafeAtomicAdd(&agg[(size_t)c * HID + 2 * lane], v.x);
        unsafeAtomicAdd(&agg[(size_t)c * HID + 2 * lane + 1], v.y);
    }
}

// ---------------- node GEMM: out = (X1*scale)@W1 [+ X2@W2] + bias, BN stats ----------------
extern "C" __global__ void __launch_bounds__(512)
k_gemm(const float* __restrict__ X1, const float* __restrict__ scale,
       const float* __restrict__ W1, const float* __restrict__ X2,
       const float* __restrict__ W2, const float* __restrict__ bias,
       float* __restrict__ out, float* __restrict__ stats, int nn)
{
    __shared__ float W1s[HID * HID];   // 64KB
    __shared__ float W2s[HID * HID];   // 64KB
    const int tid = threadIdx.x;
    const bool dual = (X2 != nullptr);
    for (int i = tid; i < HID * HID / 4; i += 512) {
        ((float4*)W1s)[i] = ((const float4*)W1)[i];
        if (dual) ((float4*)W2s)[i] = ((const float4*)W2)[i];
    }
    __syncthreads();
    const int lane = tid & 63, wv = tid >> 6;
    const int gw = blockIdx.x * 8 + wv, nwv = gridDim.x * 8;
    float2 bv = {0.f, 0.f};
    if (bias) bv = *(const float2*)&bias[2 * lane];
    float2 sm = {0.f, 0.f}, sq = {0.f, 0.f};
    for (int nb = gw * 8; nb < nn; nb += nwv * 8) {
        const int nN = min(8, nn - nb);
        float2 xA[8], xB[8];
        #pragma unroll
        for (int i = 0; i < 8; i++) {
            xA[i] = {0.f, 0.f}; xB[i] = {0.f, 0.f};
            if (i < nN) {
                xA[i] = *(const float2*)&X1[(size_t)(nb + i) * HID + 2 * lane];
                if (scale) { float sc = scale[nb + i]; xA[i].x *= sc; xA[i].y *= sc; }
                if (dual) xB[i] = *(const float2*)&X2[(size_t)(nb + i) * HID + 2 * lane];
            }
        }
        float2 acc[8];
        #pragma unroll
        for (int i = 0; i < 8; i++) acc[i] = bv;
        if (dual) {
            for (int k = 0; k < HID; k += 2) {
                float2 w1a = *(const float2*)&W1s[k * HID + 2 * lane];
                float2 w1b = *(const float2*)&W1s[(k + 1) * HID + 2 * lane];
                float2 w2a = *(const float2*)&W2s[k * HID + 2 * lane];
                float2 w2b = *(const float2*)&W2s[(k + 1) * HID + 2 * lane];
                const int kl = k >> 1;
                #pragma unroll
                for (int i = 0; i < 8; i++) {
                    float sa = rlf(xA[i].x, kl), sb = rlf(xA[i].y, kl);
                    float ta = rlf(xB[i].x, kl), tb = rlf(xB[i].y, kl);
                    acc[i].x = fmaf(sa, w1a.x, acc[i].x); acc[i].y = fmaf(sa, w1a.y, acc[i].y);
                    acc[i].x = fmaf(sb, w1b.x, acc[i].x); acc[i].y = fmaf(sb, w1b.y, acc[i].y);
                    acc[i].x = fmaf(ta, w2a.x, acc[i].x); acc[i].y = fmaf(ta, w2a.y, acc[i].y);
                    acc[i].x = fmaf(tb, w2b.x, acc[i].x); acc[i].y = fmaf(tb, w2b.y, acc[i].y);
                }
            }
        } else {
            for (int k = 0; k < HID; k += 2) {
                float2 w1a = *(const float2*)&W1s[k * HID + 2 * lane];
                float2 w1b = *(const float2*)&W1s[(k + 1) * HID + 2 * lane];
                const int kl = k >> 1;
                #pragma unroll
                for (int i = 0; i < 8; i++) {
                    float sa = rlf(xA[i].x, kl), sb = rlf(xA[i].y, kl);
                    acc[i].x = fmaf(sa, w1a.x, acc[i].x); acc[i].y = fmaf(sa, w1a.y, acc[i].y);
                    acc[i].x = fmaf(sb, w1b.x, acc[i].x); acc[i].y = fmaf(sb, w1b.y, acc[i].y);
                }
            }
        }
        #pragma unroll
        for (int i = 0; i < 8; i++) {
            if (i < nN) {
                *(float2*)&out[(size_t)(nb + i) * HID + 2 * lane] = acc[i];
                sm.x += acc[i].x; sm.y += acc[i].y;
                sq.x += acc[i].x * acc[i].x; sq.y += acc[i].y * acc[i].y;
            }
        }
    }
    unsafeAtomicAdd(&stats[2 * lane],           sm.x);
    unsafeAtomicAdd(&stats[2 * lane + 1],       sm.y);
    unsafeAtomicAdd(&stats[HID + 2 * lane],     sq.x);
    unsafeAtomicAdd(&stats[HID + 2 * lane + 1], sq.y);
}

// ---------------- h = tanh(out*sc+sh) + h (+ initial); BN finalize fused per-block ----------------
extern "C" __global__ void __launch_bounds__(256)
k_update(const float* __restrict__ outb, const float* __restrict__ stats,
         const float* __restrict__ g, const float* __restrict__ b,
         float* h, const float* __restrict__ init_, int addinit, int n4, float invn)
{
    __shared__ float scsh[2 * HID];
    if (threadIdx.x < HID) {
        int f = threadIdx.x;
        float m = stats[f] * invn;
        float v = stats[HID + f] * invn - m * m;
        float s = rsqrtf(v + EPSV) * g[f];
        scsh[f] = s;
        scsh[HID + f] = fmaf(-m, s, b[f]);
    }
    __syncthreads();
    int i = blockIdx.x * blockDim.x + threadIdx.x, st = gridDim.x * blockDim.x;
    for (; i < n4; i += st) {
        float4 o = ((const float4*)outb)[i];
        int f = (i & 31) * 4;
        float4 s  = *(const float4*)&scsh[f];
        float4 sh = *(const float4*)&scsh[HID + f];
        float4 hv = ((const float4*)h)[i];
        float4 r;
        r.x = tanhf(fmaf(o.x, s.x, sh.x)) + hv.x;
        r.y = tanhf(fmaf(o.y, s.y, sh.y)) + hv.y;
        r.z = tanhf(fmaf(o.z, s.z, sh.z)) + hv.z;
        r.w = tanhf(fmaf(o.w, s.w, sh.w)) + hv.w;
        if (addinit) {
            float4 iv = ((const float4*)init_)[i];
            r.x += iv.x; r.y += iv.y; r.z += iv.z; r.w += iv.w;
        }
        ((float4*)h)[i] = r;
    }
}

// ---------------- final: h_new = tanh(BN(out)) + h; A = h_new@W1+b1; B = h_new@W2 ----------------
// Fuses last-layer update + both edge-MLP node projections; h_new never materialized.
extern "C" __global__ void __launch_bounds__(512)
k_proj(const float* __restrict__ outb, const float* __restrict__ stats,
       const float* __restrict__ g, const float* __restrict__ b,
       const float* __restrict__ hold, const float* __restrict__ W1,
       const float* __restrict__ W2, const float* __restrict__ b1,
       float* __restrict__ outA, float* __restrict__ outB, int nn, float invn)
{
    __shared__ float W1s[HID * HID];   // 64KB
    __shared__ float W2s[HID * HID];   // 64KB
    __shared__ float scsh[2 * HID];
    const int tid = threadIdx.x;
    for (int i = tid; i < HID * HID / 4; i += 512) {
        ((float4*)W1s)[i] = ((const float4*)W1)[i];
        ((float4*)W2s)[i] = ((const float4*)W2)[i];
    }
    if (tid < HID) {
        float m = stats[tid] * invn;
        float v = stats[HID + tid] * invn - m * m;
        float s = rsqrtf(v + EPSV) * g[tid];
        scsh[tid] = s;
        scsh[HID + tid] = fmaf(-m, s, b[tid]);
    }
    __syncthreads();
    const int lane = tid & 63, wv = tid >> 6;
    const int gw = blockIdx.x * 8 + wv, nwv = gridDim.x * 8;
    const float2 sA  = *(const float2*)&scsh[2 * lane];
    const float2 shA = *(const float2*)&scsh[HID + 2 * lane];
    float2 bv = *(const float2*)&b1[2 * lane];
    for (int nb = gw * 8; nb < nn; nb += nwv * 8) {
        const int nN = min(8, nn - nb);
        float2 xH[8];
        #pragma unroll
        for (int i = 0; i < 8; i++) {
            xH[i] = {0.f, 0.f};
            if (i < nN) {
                float2 o  = *(const float2*)&outb[(size_t)(nb + i) * HID + 2 * lane];
                float2 hv = *(const float2*)&hold[(size_t)(nb + i) * HID + 2 * lane];
                xH[i].x = tanhf(fmaf(o.x, sA.x, shA.x)) + hv.x;
                xH[i].y = tanhf(fmaf(o.y, sA.y, shA.y)) + hv.y;
            }
        }
        float2 accA[8], accB[8];
        #pragma unroll
        for (int i = 0; i < 8; i++) { accA[i] = bv; accB[i] = {0.f, 0.f}; }
        for (int k = 0; k < HID; k += 2) {
            float2 w1a = *(const float2*)&W1s[k * HID + 2 * lane];
            float2 w1b = *(const float2*)&W1s[(k + 1) * HID + 2 * lane];
            float2 w2a = *(const float2*)&W2s[k * HID + 2 * lane];
            float2 w2b = *(const float2*)&W2s[(k + 1) * HID + 2 * lane];
            const int kl = k >> 1;
            #pragma unroll
            for (int i = 0; i < 8; i++) {
                float sa = rlf(xH[i].x, kl), sb = rlf(xH[i].y, kl);
                accA[i].x = fmaf(sa, w1a.x, accA[i].x); accA[i].y = fmaf(sa, w1a.y, accA[i].y);
                accA[i].x = fmaf(sb, w1b.x, accA[i].x); accA[i].y = fmaf(sb, w1b.y, accA[i].y);
                accB[i].x = fmaf(sa, w2a.x, accB[i].x); accB[i].y = fmaf(sa, w2a.y, accB[i].y);
                accB[i].x = fmaf(sb, w2b.x, accB[i].x); accB[i].y = fmaf(sb, w2b.y, accB[i].y);
            }
        }
        #pragma unroll
        for (int i = 0; i < 8; i++) {
            if (i < nN) {
                *(float2*)&outA[(size_t)(nb + i) * HID + 2 * lane] = accA[i];
                *(float2*)&outB[(size_t)(nb + i) * HID + 2 * lane] = accB[i];
            }
        }
    }
}

// ---------------- fused edge MLP (r4 structure + pointer strength reduction) ----------------
extern "C" __global__ void __launch_bounds__(256)
k_edge(const float* __restrict__ A, const float* __restrict__ B,
       const float* __restrict__ eattr, const int* __restrict__ row,
       const int* __restrict__ col, const float* __restrict__ We1e,
       const float* __restrict__ We2, const float* __restrict__ be2,
       const float* __restrict__ We3, const float* __restrict__ be3,
       float* __restrict__ outp, int beg, int end, int ne)
{
    __shared__ float zbuf[32][132];     // swizzled z
    __shared__ float tbuf[4][32][8];    // per-wave partial edge sums
    const int tid = threadIdx.x, lane = tid & 63, wv = tid >> 6;
    float2 w1r[16];
    #pragma unroll
    for (int j = 0; j < 16; j++) w1r[j] = *(const float2*)&We1e[j * HID + 2 * lane];
    const int fi = lane & 7, ks = lane >> 3;
    const int f0 = 16 * wv + 2 * fi;
    float w2r0[16], w2r1[16];
    #pragma unroll
    for (int m = 0; m < 16; m++) {
        w2r0[m] = We2[(16 * ks + m) * 64 + f0];
        w2r1[m] = We2[(16 * ks + m) * 64 + f0 + 1];
    }
    const float b20 = be2[f0], b21 = be2[f0 + 1];
    const float w30 = We3[f0], w31 = We3[f0 + 1];
    const float bias3 = be3[0];
    const int wcol4 = (((lane >> 1) & 3) << 3) | ((lane >> 1) >> 2);
    const int woff = wcol4 * 4 + (lane & 1) * 2;
    for (int cb = beg + blockIdx.x * 32; cb < end; cb += gridDim.x * 32) {
        // ---- phase A ----
        const int e0 = cb + wv * 8;
        float2 ear = {0.f, 0.f};
        if (e0 + (lane >> 3) < ne) ear = *(const float2*)&eattr[(size_t)e0 * EIN + 2 * lane];
        int rr[8], cc[8];
        #pragma unroll
        for (int i = 0; i < 8; i++) {
            const int e = e0 + i;
            rr[i] = (e < ne) ? row[e] : 0;
            cc[i] = (e < ne) ? col[e] : 0;
        }
        float2 av[8], bv8[8];
        #pragma unroll
        for (int i = 0; i < 8; i++) {
            av[i]  = *(const float2*)&A[(size_t)rr[i] * HID + 2 * lane];
            bv8[i] = *(const float2*)&B[(size_t)cc[i] * HID + 2 * lane];
        }
        float* zw = &zbuf[wv * 8][woff];
        #pragma unroll
        for (int i = 0; i < 8; i++) {
            float2 q; q.x = av[i].x + bv8[i].x; q.y = av[i].y + bv8[i].y;
            #pragma unroll
            for (int j = 0; j < 16; j++) {
                float s = rlf((j & 1) ? ear.y : ear.x, i * 8 + (j >> 1));
                q.x = fmaf(s, w1r[j].x, q.x);
                q.y = fmaf(s, w1r[j].y, q.y);
            }
            q.x = fmaxf(q.x, 0.f); q.y = fmaxf(q.y, 0.f);
            *(float2*)zw = q;
            zw += 132;
        }
        __syncthreads();
        // ---- phase B (strength-reduced zbuf pointer, 2-edge ILP) ----
        const float* zp = &zbuf[0][ks * 4];
        #pragma unroll 2
        for (int e = 0; e < 32; e++) {
            float4 z0 = *(const float4*)(zp);
            float4 z1 = *(const float4*)(zp + 32);
            float4 z2 = *(const float4*)(zp + 64);
            float4 z3 = *(const float4*)(zp + 96);
            zp += 132;
            float acc0 = 0.f, acc1 = 0.f;
            acc0 = fmaf(z0.x, w2r0[0],  acc0); acc1 = fmaf(z0.x, w2r1[0],  acc1);
            acc0 = fmaf(z0.y, w2r0[1],  acc0); acc1 = fmaf(z0.y, w2r1[1],  acc1);
            acc0 = fmaf(z0.z, w2r0[2],  acc0); acc1 = fmaf(z0.z, w2r1[2],  acc1);
            acc0 = fmaf(z0.w, w2r0[3],  acc0); acc1 = fmaf(z0.w, w2r1[3],  acc1);
            acc0 = fmaf(z1.x, w2r0[4],  acc0); acc1 = fmaf(z1.x, w2r1[4],  acc1);
            acc0 = fmaf(z1.y, w2r0[5],  acc0); acc1 = fmaf(z1.y, w2r1[5],  acc1);
            acc0 = fmaf(z1.z, w2r0[6],  acc0); acc1 = fmaf(z1.z, w2r1[6],  acc1);
            acc0 = fmaf(z1.w, w2r0[7],  acc0); acc1 = fmaf(z1.w, w2r1[7],  acc1);
            acc0 = fmaf(z2.x, w2r0[8],  acc0); acc1 = fmaf(z2.x, w2r1[8],  acc1);
            acc0 = fmaf(z2.y, w2r0[9],  acc0); acc1 = fmaf(z2.y, w2r1[9],  acc1);
            acc0 = fmaf(z2.z, w2r0[10], acc0); acc1 = fmaf(z2.z, w2r1[10], acc1);
            acc0 = fmaf(z2.w, w2r0[11], acc0); acc1 = fmaf(z2.w, w2r1[11], acc1);
            acc0 = fmaf(z3.x, w2r0[12], acc0); acc1 = fmaf(z3.x, w2r1[12], acc1);
            acc0 = fmaf(z3.y, w2r0[13], acc0); acc1 = fmaf(z3.y, w2r1[13], acc1);
            acc0 = fmaf(z3.z, w2r0[14], acc0); acc1 = fmaf(z3.z, w2r1[14], acc1);
            acc0 = fmaf(z3.w, w2r0[15], acc0); acc1 = fmaf(z3.w, w2r1[15], acc1);
            acc0 += __shfl_xor(acc0, 8);  acc1 += __shfl_xor(acc1, 8);
            acc0 += __shfl_xor(acc0, 16); acc1 += __shfl_xor(acc1, 16);
            acc0 += __shfl_xor(acc0, 32); acc1 += __shfl_xor(acc1, 32);
            float o0 = fmaxf(acc0 + b20, 0.f), o1 = fmaxf(acc1 + b21, 0.f);
            float t3 = fmaf(o0, w30, o1 * w31);
            if (ks == 0) tbuf[wv][e][fi] = t3;
        }
        __syncthreads();
        {
            const int e = tid >> 3, p = tid & 7;
            float s = (tbuf[0][e][p] + tbuf[1][e][p]) + (tbuf[2][e][p] + tbuf[3][e][p]);
            s += __shfl_xor(s, 1); s += __shfl_xor(s, 2); s += __shfl_xor(s, 4);
            if (p == 0 && cb + e < end) outp[cb + e] = s + bias3;
        }
        __syncthreads();
    }
}

extern "C" void kernel_launch(void* const* d_in, const int* in_sizes, int n_in,
                              void* d_out, int out_size, void* d_ws, size_t ws_size,
                              hipStream_t stream)
{
    const float* x     = (const float*)d_in[0];
    const float* eattr = (const float*)d_in[1];
    const float* etab  = (const float*)d_in[2];
    const float* lng   = (const float*)d_in[3];
    const float* lnb   = (const float*)d_in[4];
    const float* Win   = (const float*)d_in[5];
    const float* bin   = (const float*)d_in[6];
    const float* Wl    = (const float*)d_in[7];
    const float* bl    = (const float*)d_in[8];
    const float* Wr    = (const float*)d_in[9];
    const float* bng   = (const float*)d_in[10];
    const float* bnb   = (const float*)d_in[11];
    const float* We1   = (const float*)d_in[12];
    const float* be1   = (const float*)d_in[13];
    const float* We2   = (const float*)d_in[14];
    const float* be2   = (const float*)d_in[15];
    const float* We3   = (const float*)d_in[16];
    const float* be3   = (const float*)d_in[17];
    const int*   eidx  = (const int*)d_in[18];
    const int*   nidx  = (const int*)d_in[19];

    const int nn = in_sizes[0] / NIN;     // 100000
    const int ne = in_sizes[1] / EIN;     // 1600000
    const int* row = eidx;
    const int* col = eidx + ne;
    const float invn = 1.0f / nn;

    float* ws = (float*)d_ws;
    const size_t big = (size_t)nn * HID;
    float* h    = ws;                 // N*128
    float* bufB = ws + big;           // N*128  (initial; later B-projection)
    float* bufA = ws + 2 * big;       // N*128  (agg / gemm-out; later A-projection)
    float* tail = ws + 3 * big;

    const size_t need_csr = (3 * big + 3 * (size_t)nn + 1 + (size_t)ne + 512) * 4;
    const bool use_csr = (ws_size >= need_csr);

    if (use_csr) {
        int*   degi  = (int*)tail;                  // N
        int*   offs  = degi + nn;                   // N+1
        int*   cur   = offs + nn + 1;               // N
        int*   csr   = cur + nn;                    // E
        float* stats = (float*)(csr + ne);          // 256

        k_input<<<512, 256, 0, stream>>>(x, etab, nidx, lng, lnb, Win, bin, h, bufB,
                                         degi, cur, nn);
        k_deg<<<1024, 256, 0, stream>>>(col, degi, ne);
        k_scan<<<1, 1024, 0, stream>>>(degi, offs, nn);
        k_fill<<<1024, 256, 0, stream>>>(row, col, offs, cur, csr, ne);

        for (int i = 0; i < 3; i++) {
            k_agg<<<2048, 256, 0, stream>>>(h, offs, csr, bufA, stats, nn);
            k_gemm<<<256, 512, 0, stream>>>(bufA, nullptr, Wl + (size_t)i * HID * HID,
                                            h, Wr + (size_t)i * HID * HID, bl + i * HID,
                                            bufA, stats, nn);
            if (i < 2) {
                k_update<<<1024, 256, 0, stream>>>(bufA, stats, bng + i * HID, bnb + i * HID,
                                                   h, bufB, i & 1, nn * HID / 4, invn);
            } else {
                k_proj<<<256, 512, 0, stream>>>(bufA, stats, bng + i * HID, bnb + i * HID,
                                                h, We1, We1 + HID * HID, be1,
                                                bufA, bufB, nn, invn);
            }
        }
    } else {
        float* deg   = tail;                        // N
        float* inv   = deg + nn;                    // N
        float* stats = inv + nn;                    // 256

        k_input<<<512, 256, 0, stream>>>(x, etab, nidx, lng, lnb, Win, bin, h, bufB,
                                         nullptr, nullptr, nn);
        hipMemsetAsync(deg, 0, (size_t)nn * 4, stream);
        k_degf<<<1024, 256, 0, stream>>>(col, deg, ne);
        k_invdeg<<<(nn + 255) / 256, 256, 0, stream>>>(deg, inv, nn);

        for (int i = 0; i < 3; i++) {
            hipMemsetAsync(bufA, 0, big * 4, stream);
            k_scatter<<<2048, 256, 0, stream>>>(h, row, col, bufA, stats, ne);
            k_gemm<<<256, 512, 0, stream>>>(bufA, inv, Wl + (size_t)i * HID * HID,
                                            h, Wr + (size_t)i * HID * HID, bl + i * HID,
                                            bufA, stats, nn);
            if (i < 2) {
                k_update<<<1024, 256, 0, stream>>>(bufA, stats, bng + i * HID, bnb + i * HID,
                                                   h, bufB, i & 1, nn * HID / 4, invn);
            } else {
                k_proj<<<256, 512, 0, stream>>>(bufA, stats, bng + i * HID, bnb + i * HID,
                                                h, We1, We1 + HID * HID, be1,
                                                bufA, bufB, nn, invn);
            }
        }
    }

    const int half = (ne / 2) & ~31;
    k_edge<<<1792, 256, 0, stream>>>(bufA, bufB, eattr, row, col,
                                     We1 + 2 * HID * HID, We2, be2, We3, be3,
                                     (float*)d_out, 0, half, ne);
    k_edge<<<1792, 256, 0, stream>>>(bufA, bufB, eattr, row, col,
                                     We1 + 2 * HID * HID, We2, be2, We3, be3,
                                     (float*)d_out, half, ne, ne);
}

// Round 10
// 2685.322 us; speedup vs baseline: 1.2223x; 1.0787x over previous
//
#include <hip/hip_runtime.h>
#include <hip/hip_bf16.h>
#include <cstddef>

#define HID 128
#define EMBD 32
#define NIN 32
#define EIN 16
#define EPSV 1e-5f

__device__ __forceinline__ float rlf(float v, int l) {
    return __int_as_float(__builtin_amdgcn_readlane(__float_as_int(v), l));
}

// ---------------- embedding + layernorm + input projection (+ zero degi/cur) ----------------
extern "C" __global__ void __launch_bounds__(256)
k_input(const float* __restrict__ x, const float* __restrict__ etab,
        const int* __restrict__ nidx, const float* __restrict__ lng_,
        const float* __restrict__ lnb_, const float* __restrict__ Win,
        const float* __restrict__ bin_, float* __restrict__ h,
        float* __restrict__ init_, int* __restrict__ zi, int* __restrict__ zc, int nn)
{
    __shared__ float Ws[64 * HID];           // 32KB
    __shared__ float lng[EMBD], lnb[EMBD], bin[HID];
    __shared__ float xbuf[4][64];
    if (zi) {
        int gid = blockIdx.x * blockDim.x + threadIdx.x, st = gridDim.x * blockDim.x;
        for (int i = gid; i < nn; i += st) { zi[i] = 0; zc[i] = 0; }
    }
    for (int i = threadIdx.x; i < 64 * HID; i += 256) Ws[i] = Win[i];
    if (threadIdx.x < EMBD) { lng[threadIdx.x] = lng_[threadIdx.x]; lnb[threadIdx.x] = lnb_[threadIdx.x]; }
    if (threadIdx.x < HID) bin[threadIdx.x] = bin_[threadIdx.x];
    __syncthreads();
    const int wv = threadIdx.x >> 6, lane = threadIdx.x & 63;
    const int w0 = blockIdx.x * 4 + wv, nw = gridDim.x * 4;
    for (int n = w0; n < nn; n += nw) {
        float e = 0.f;
        if (lane < EMBD) e = etab[(size_t)nidx[n] * EMBD + lane];
        float s = e, q = e * e;
        #pragma unroll
        for (int o = 16; o; o >>= 1) { s += __shfl_xor(s, o, 32); q += __shfl_xor(q, o, 32); }
        if (lane < EMBD) {
            float m = s * (1.f / EMBD);
            float v = q * (1.f / EMBD) - m * m;
            xbuf[wv][lane] = (e - m) * rsqrtf(v + EPSV) * lng[lane] + lnb[lane];
        } else {
            xbuf[wv][lane] = x[(size_t)n * NIN + (lane - NIN)];
        }
        float2 a0 = *(const float2*)&bin[2 * lane], a1 = {0.f, 0.f};
        #pragma unroll 8
        for (int k = 0; k < 64; k += 2) {
            float2 wA = *(const float2*)&Ws[k * HID + 2 * lane];
            float2 wB = *(const float2*)&Ws[(k + 1) * HID + 2 * lane];
            a0.x = fmaf(xbuf[wv][k], wA.x, a0.x);     a0.y = fmaf(xbuf[wv][k], wA.y, a0.y);
            a1.x = fmaf(xbuf[wv][k + 1], wB.x, a1.x); a1.y = fmaf(xbuf[wv][k + 1], wB.y, a1.y);
        }
        float2 r; r.x = fmaxf(a0.x + a1.x, 0.f); r.y = fmaxf(a0.y + a1.y, 0.f);
        *(float2*)&h[(size_t)n * HID + 2 * lane] = r;
        *(float2*)&init_[(size_t)n * HID + 2 * lane] = r;
    }
}

// ---------------- CSR build ----------------
extern "C" __global__ void k_deg(const int* __restrict__ col, int* __restrict__ degi, int ne) {
    int i = blockIdx.x * blockDim.x + threadIdx.x, st = gridDim.x * blockDim.x;
    for (; i < ne; i += st) atomicAdd(&degi[col[i]], 1);
}

extern "C" __global__ void __launch_bounds__(1024)
k_scan(const int* __restrict__ degi, int* __restrict__ offs, int nn) {
    __shared__ int ps[1024];
    const int t = threadIdx.x;
    const int per = (nn + 1023) / 1024;
    const int s = min(t * per, nn), e = min(s + per, nn);
    int sum = 0;
    for (int i = s; i < e; i++) sum += degi[i];
    ps[t] = sum;
    __syncthreads();
    for (int off = 1; off < 1024; off <<= 1) {
        int v = (t >= off) ? ps[t - off] : 0;
        __syncthreads();
        ps[t] += v;
        __syncthreads();
    }
    int run = (t ? ps[t - 1] : 0);
    for (int i = s; i < e; i++) { offs[i] = run; run += degi[i]; }
    if (t == 1023) offs[nn] = run;
}

extern "C" __global__ void k_fill(const int* __restrict__ row, const int* __restrict__ col,
                                  const int* __restrict__ offs, int* __restrict__ cur,
                                  int* __restrict__ csr, int ne) {
    int i = blockIdx.x * blockDim.x + threadIdx.x, st = gridDim.x * blockDim.x;
    for (; i < ne; i += st) {
        int c = col[i];
        int p = atomicAdd(&cur[c], 1);
        csr[offs[c] + p] = row[i];
    }
}

// ---------------- CSR aggregation (+ zero stats for next gemm) ----------------
extern "C" __global__ void __launch_bounds__(256)
k_agg(const float* __restrict__ h, const int* __restrict__ offs,
      const int* __restrict__ csr, float* __restrict__ agg,
      float* __restrict__ stats, int nn)
{
    if (blockIdx.x == 0 && threadIdx.x < 2 * HID) stats[threadIdx.x] = 0.f;
    const int lane = threadIdx.x & 63;
    int w = blockIdx.x * 4 + (threadIdx.x >> 6), nw = gridDim.x * 4;
    for (int n = w; n < nn; n += nw) {
        const int o0 = offs[n], o1 = offs[n + 1];
        float2 acc0 = {0.f, 0.f}, acc1 = {0.f, 0.f};
        int j = o0;
        for (; j + 8 <= o1; j += 8) {
            int s[8];
            #pragma unroll
            for (int i = 0; i < 8; i++) s[i] = csr[j + i];
            float2 v[8];
            #pragma unroll
            for (int i = 0; i < 8; i++) v[i] = *(const float2*)&h[(size_t)s[i] * HID + 2 * lane];
            #pragma unroll
            for (int i = 0; i < 8; i += 2) {
                acc0.x += v[i].x;     acc0.y += v[i].y;
                acc1.x += v[i + 1].x; acc1.y += v[i + 1].y;
            }
        }
        for (; j < o1; j++) {
            int s0 = csr[j];
            float2 v0 = *(const float2*)&h[(size_t)s0 * HID + 2 * lane];
            acc0.x += v0.x; acc0.y += v0.y;
        }
        const float idg = 1.f / fmaxf((float)(o1 - o0), 1.f);
        float2 r; r.x = (acc0.x + acc1.x) * idg; r.y = (acc0.y + acc1.y) * idg;
        *(float2*)&agg[(size_t)n * HID + 2 * lane] = r;
    }
}

// ---------------- atomic-scatter fallback path ----------------
extern "C" __global__ void k_degf(const int* __restrict__ col, float* __restrict__ deg, int ne) {
    int i = blockIdx.x * blockDim.x + threadIdx.x, st = gridDim.x * blockDim.x;
    for (; i < ne; i += st) unsafeAtomicAdd(&deg[col[i]], 1.f);
}
extern "C" __global__ void k_invdeg(const float* __restrict__ deg, float* __restrict__ inv, int nn) {
    int i = blockIdx.x * blockDim.x + threadIdx.x;
    if (i < nn) inv[i] = 1.f / fmaxf(deg[i], 1.f);
}
extern "C" __global__ void __launch_bounds__(256)
k_scatter(const float* __restrict__ h, const int* __restrict__ row,
          const int* __restrict__ col, float* agg, float* __restrict__ stats, int ne)
{
    if (blockIdx.x == 0 && threadIdx.x < 2 * HID) stats[threadIdx.x] = 0.f;
    const int lane = threadIdx.x & 63;
    int w = blockIdx.x * 4 + (threadIdx.x >> 6), nw = gridDim.x * 4;
    for (int e = w; e < ne; e += nw) {
        int r = row[e], c = col[e];
        float2 v = *(const float2*)&h[(size_t)r * HID + 2 * lane];
        unsafeAtomicAdd(&agg[(size_t)c * HID + 2 * lane], v.x);
        unsafeAtomicAdd(&agg[(size_t)c * HID + 2 * lane + 1], v.y);
    }
}

// ---------------- node GEMM: out = (X1*scale)@W1 [+ X2@W2] + bias, BN stats ----------------
// 768 threads (12 waves): 3 waves/SIMD at 1 block/CU (128KB LDS).
extern "C" __global__ void __launch_bounds__(768)
k_gemm(const float* __restrict__ X1, const float* __restrict__ scale,
       const float* __restrict__ W1, const float* __restrict__ X2,
       const float* __restrict__ W2, const float* __restrict__ bias,
       float* __restrict__ out, float* __restrict__ stats, int nn)
{
    __shared__ float W1s[HID * HID];   // 64KB
    __shared__ float W2s[HID * HID];   // 64KB
    const int tid = threadIdx.x;
    const bool dual = (X2 != nullptr);
    for (int i = tid; i < HID * HID / 4; i += 768) {
        ((float4*)W1s)[i] = ((const float4*)W1)[i];
        if (dual) ((float4*)W2s)[i] = ((const float4*)W2)[i];
    }
    __syncthreads();
    const int lane = tid & 63, wv = tid >> 6;          // wv in [0,12)
    const int gw = blockIdx.x * 12 + wv, nwv = gridDim.x * 12;
    float2 bv = {0.f, 0.f};
    if (bias) bv = *(const float2*)&bias[2 * lane];
    float2 sm = {0.f, 0.f}, sq = {0.f, 0.f};
    for (int nb = gw * 8; nb < nn; nb += nwv * 8) {
        const int nN = min(8, nn - nb);
        float2 xA[8], xB[8];
        #pragma unroll
        for (int i = 0; i < 8; i++) {
            xA[i] = {0.f, 0.f}; xB[i] = {0.f, 0.f};
            if (i < nN) {
                xA[i] = *(const float2*)&X1[(size_t)(nb + i) * HID + 2 * lane];
                if (scale) { float sc = scale[nb + i]; xA[i].x *= sc; xA[i].y *= sc; }
                if (dual) xB[i] = *(const float2*)&X2[(size_t)(nb + i) * HID + 2 * lane];
            }
        }
        float2 acc[8];
        #pragma unroll
        for (int i = 0; i < 8; i++) acc[i] = bv;
        if (dual) {
            for (int k = 0; k < HID; k += 2) {
                float2 w1a = *(const float2*)&W1s[k * HID + 2 * lane];
                float2 w1b = *(const float2*)&W1s[(k + 1) * HID + 2 * lane];
                float2 w2a = *(const float2*)&W2s[k * HID + 2 * lane];
                float2 w2b = *(const float2*)&W2s[(k + 1) * HID + 2 * lane];
                const int kl = k >> 1;
                #pragma unroll
                for (int i = 0; i < 8; i++) {
                    float sa = rlf(xA[i].x, kl), sb = rlf(xA[i].y, kl);
                    float ta = rlf(xB[i].x, kl), tb = rlf(xB[i].y, kl);
                    acc[i].x = fmaf(sa, w1a.x, acc[i].x); acc[i].y = fmaf(sa, w1a.y, acc[i].y);
                    acc[i].x = fmaf(sb, w1b.x, acc[i].x); acc[i].y = fmaf(sb, w1b.y, acc[i].y);
                    acc[i].x = fmaf(ta, w2a.x, acc[i].x); acc[i].y = fmaf(ta, w2a.y, acc[i].y);
                    acc[i].x = fmaf(tb, w2b.x, acc[i].x); acc[i].y = fmaf(tb, w2b.y, acc[i].y);
                }
            }
        } else {
            for (int k = 0; k < HID; k += 2) {
                float2 w1a = *(const float2*)&W1s[k * HID + 2 * lane];
                float2 w1b = *(const float2*)&W1s[(k + 1) * HID + 2 * lane];
                const int kl = k >> 1;
                #pragma unroll
                for (int i = 0; i < 8; i++) {
                    float sa = rlf(xA[i].x, kl), sb = rlf(xA[i].y, kl);
                    acc[i].x = fmaf(sa, w1a.x, acc[i].x); acc[i].y = fmaf(sa, w1a.y, acc[i].y);
                    acc[i].x = fmaf(sb, w1b.x, acc[i].x); acc[i].y = fmaf(sb, w1b.y, acc[i].y);
                }
            }
        }
        #pragma unroll
        for (int i = 0; i < 8; i++) {
            if (i < nN) {
                *(float2*)&out[(size_t)(nb + i) * HID + 2 * lane] = acc[i];
                sm.x += acc[i].x; sm.y += acc[i].y;
                sq.x += acc[i].x * acc[i].x; sq.y += acc[i].y * acc[i].y;
            }
        }
    }
    unsafeAtomicAdd(&stats[2 * lane],           sm.x);
    unsafeAtomicAdd(&stats[2 * lane + 1],       sm.y);
    unsafeAtomicAdd(&stats[HID + 2 * lane],     sq.x);
    unsafeAtomicAdd(&stats[HID + 2 * lane + 1], sq.y);
}

// ---------------- h = tanh(out*sc+sh) + h (+ initial); BN finalize fused per-block ----------------
extern "C" __global__ void __launch_bounds__(256)
k_update(const float* __restrict__ outb, const float* __restrict__ stats,
         const float* __restrict__ g, const float* __restrict__ b,
         float* h, const float* __restrict__ init_, int addinit, int n4, float invn)
{
    __shared__ float scsh[2 * HID];
    if (threadIdx.x < HID) {
        int f = threadIdx.x;
        float m = stats[f] * invn;
        float v = stats[HID + f] * invn - m * m;
        float s = rsqrtf(v + EPSV) * g[f];
        scsh[f] = s;
        scsh[HID + f] = fmaf(-m, s, b[f]);
    }
    __syncthreads();
    int i = blockIdx.x * blockDim.x + threadIdx.x, st = gridDim.x * blockDim.x;
    for (; i < n4; i += st) {
        float4 o = ((const float4*)outb)[i];
        int f = (i & 31) * 4;
        float4 s  = *(const float4*)&scsh[f];
        float4 sh = *(const float4*)&scsh[HID + f];
        float4 hv = ((const float4*)h)[i];
        float4 r;
        r.x = tanhf(fmaf(o.x, s.x, sh.x)) + hv.x;
        r.y = tanhf(fmaf(o.y, s.y, sh.y)) + hv.y;
        r.z = tanhf(fmaf(o.z, s.z, sh.z)) + hv.z;
        r.w = tanhf(fmaf(o.w, s.w, sh.w)) + hv.w;
        if (addinit) {
            float4 iv = ((const float4*)init_)[i];
            r.x += iv.x; r.y += iv.y; r.z += iv.z; r.w += iv.w;
        }
        ((float4*)h)[i] = r;
    }
}

// ---------------- final: h_new = tanh(BN(out)) + h; A = h_new@W1+b1; B = h_new@W2 ----------------
extern "C" __global__ void __launch_bounds__(768)
k_proj(const float* __restrict__ outb, const float* __restrict__ stats,
       const float* __restrict__ g, const float* __restrict__ b,
       const float* __restrict__ hold, const float* __restrict__ W1,
       const float* __restrict__ W2, const float* __restrict__ b1,
       float* __restrict__ outA, float* __restrict__ outB, int nn, float invn)
{
    __shared__ float W1s[HID * HID];   // 64KB
    __shared__ float W2s[HID * HID];   // 64KB
    __shared__ float scsh[2 * HID];
    const int tid = threadIdx.x;
    for (int i = tid; i < HID * HID / 4; i += 768) {
        ((float4*)W1s)[i] = ((const float4*)W1)[i];
        ((float4*)W2s)[i] = ((const float4*)W2)[i];
    }
    if (tid < HID) {
        float m = stats[tid] * invn;
        float v = stats[HID + tid] * invn - m * m;
        float s = rsqrtf(v + EPSV) * g[tid];
        scsh[tid] = s;
        scsh[HID + tid] = fmaf(-m, s, b[tid]);
    }
    __syncthreads();
    const int lane = tid & 63, wv = tid >> 6;          // wv in [0,12)
    const int gw = blockIdx.x * 12 + wv, nwv = gridDim.x * 12;
    const float2 sA  = *(const float2*)&scsh[2 * lane];
    const float2 shA = *(const float2*)&scsh[HID + 2 * lane];
    float2 bv = *(const float2*)&b1[2 * lane];
    for (int nb = gw * 8; nb < nn; nb += nwv * 8) {
        const int nN = min(8, nn - nb);
        float2 xH[8];
        #pragma unroll
        for (int i = 0; i < 8; i++) {
            xH[i] = {0.f, 0.f};
            if (i < nN) {
                float2 o  = *(const float2*)&outb[(size_t)(nb + i) * HID + 2 * lane];
                float2 hv = *(const float2*)&hold[(size_t)(nb + i) * HID + 2 * lane];
                xH[i].x = tanhf(fmaf(o.x, sA.x, shA.x)) + hv.x;
                xH[i].y = tanhf(fmaf(o.y, sA.y, shA.y)) + hv.y;
            }
        }
        float2 accA[8], accB[8];
        #pragma unroll
        for (int i = 0; i < 8; i++) { accA[i] = bv; accB[i] = {0.f, 0.f}; }
        for (int k = 0; k < HID; k += 2) {
            float2 w1a = *(const float2*)&W1s[k * HID + 2 * lane];
            float2 w1b = *(const float2*)&W1s[(k + 1) * HID + 2 * lane];
            float2 w2a = *(const float2*)&W2s[k * HID + 2 * lane];
            float2 w2b = *(const float2*)&W2s[(k + 1) * HID + 2 * lane];
            const int kl = k >> 1;
            #pragma unroll
            for (int i = 0; i < 8; i++) {
                float sa = rlf(xH[i].x, kl), sb = rlf(xH[i].y, kl);
                accA[i].x = fmaf(sa, w1a.x, accA[i].x); accA[i].y = fmaf(sa, w1a.y, accA[i].y);
                accA[i].x = fmaf(sb, w1b.x, accA[i].x); accA[i].y = fmaf(sb, w1b.y, accA[i].y);
                accB[i].x = fmaf(sa, w2a.x, accB[i].x); accB[i].y = fmaf(sa, w2a.y, accB[i].y);
                accB[i].x = fmaf(sb, w2b.x, accB[i].x); accB[i].y = fmaf(sb, w2b.y, accB[i].y);
            }
        }
        #pragma unroll
        for (int i = 0; i < 8; i++) {
            if (i < nN) {
                *(float2*)&outA[(size_t)(nb + i) * HID + 2 * lane] = accA[i];
                *(float2*)&outB[(size_t)(nb + i) * HID + 2 * lane] = accB[i];
            }
        }
    }
}

// ---------------- fused edge MLP ----------------
// Phase A: wave computes z for its own 8 edges (W1e in VGPRs, ea via readlane),
//   z -> bank-swizzled LDS (logical col4 c -> ((c&3)<<3)|(c>>2)).
// Phase B (NEW 4-way k-split): fi=lane&15 -> features {32*(wv&1)+2fi, +1};
//   ks=lane>>4 -> k in [32ks, 32ks+32). Wave handles 16 edges ((wv>>1)*16..+16).
//   Per edge: 8 conflict-free b128 z reads + 64 fmaf + only 4 shfl (2 per acc).
extern "C" __global__ void __launch_bounds__(256)
k_edge(const float* __restrict__ A, const float* __restrict__ B,
       const float* __restrict__ eattr, const int* __restrict__ row,
       const int* __restrict__ col, const float* __restrict__ We1e,
       const float* __restrict__ We2, const float* __restrict__ be2,
       const float* __restrict__ We3, const float* __restrict__ be3,
       float* __restrict__ outp, int beg, int end, int ne)
{
    __shared__ float zbuf[32][132];     // swizzled z
    __shared__ float tbuf[2][32][16];   // [feature-half][edge][fi] partials
    const int tid = threadIdx.x, lane = tid & 63, wv = tid >> 6;
    float2 w1r[16];
    #pragma unroll
    for (int j = 0; j < 16; j++) w1r[j] = *(const float2*)&We1e[j * HID + 2 * lane];
    const int fi = lane & 15, ks = lane >> 4;
    const int fh = wv & 1;              // feature half (0: f 0-63? no: 0-31, 1: 32-63)
    const int ebase = (wv >> 1) * 16;   // edge half for phase B
    const int f0 = 32 * fh + 2 * fi;
    float w2r0[32], w2r1[32];
    #pragma unroll
    for (int m = 0; m < 32; m++) {
        w2r0[m] = We2[(32 * ks + m) * 64 + f0];
        w2r1[m] = We2[(32 * ks + m) * 64 + f0 + 1];
    }
    const float b20 = be2[f0], b21 = be2[f0 + 1];
    const float w30 = We3[f0], w31 = We3[f0 + 1];
    const float bias3 = be3[0];
    const int wcol4 = (((lane >> 1) & 3) << 3) | ((lane >> 1) >> 2);
    const int woff = wcol4 * 4 + (lane & 1) * 2;
    for (int cb = beg + blockIdx.x * 32; cb < end; cb += gridDim.x * 32) {
        // ---- phase A ----
        const int e0 = cb + wv * 8;
        float2 ear = {0.f, 0.f};
        if (e0 + (lane >> 3) < ne) ear = *(const float2*)&eattr[(size_t)e0 * EIN + 2 * lane];
        int rr[8], cc[8];
        #pragma unroll
        for (int i = 0; i < 8; i++) {
            const int e = e0 + i;
            rr[i] = (e < ne) ? row[e] : 0;
            cc[i] = (e < ne) ? col[e] : 0;
        }
        float2 av[8], bv8[8];
        #pragma unroll
        for (int i = 0; i < 8; i++) {
            av[i]  = *(const float2*)&A[(size_t)rr[i] * HID + 2 * lane];
            bv8[i] = *(const float2*)&B[(size_t)cc[i] * HID + 2 * lane];
        }
        float* zw = &zbuf[wv * 8][woff];
        #pragma unroll
        for (int i = 0; i < 8; i++) {
            float2 q; q.x = av[i].x + bv8[i].x; q.y = av[i].y + bv8[i].y;
            #pragma unroll
            for (int j = 0; j < 16; j++) {
                float s = rlf((j & 1) ? ear.y : ear.x, i * 8 + (j >> 1));
                q.x = fmaf(s, w1r[j].x, q.x);
                q.y = fmaf(s, w1r[j].y, q.y);
            }
            q.x = fmaxf(q.x, 0.f); q.y = fmaxf(q.y, 0.f);
            *(float2*)zw = q;
            zw += 132;
        }
        __syncthreads();
        // ---- phase B (4-way k-split, 16 edges/wave) ----
        const float* zq = &zbuf[ebase][8 * ks];
#define FQ(Z, M) \
            acc0 = fmaf(Z.x, w2r0[M],     acc0); acc1 = fmaf(Z.x, w2r1[M],     acc1); \
            acc0 = fmaf(Z.y, w2r0[(M)+1], acc0); acc1 = fmaf(Z.y, w2r1[(M)+1], acc1); \
            acc0 = fmaf(Z.z, w2r0[(M)+2], acc0); acc1 = fmaf(Z.z, w2r1[(M)+2], acc1); \
            acc0 = fmaf(Z.w, w2r0[(M)+3], acc0); acc1 = fmaf(Z.w, w2r1[(M)+3], acc1);
        #pragma unroll 2
        for (int e2 = 0; e2 < 16; e2++) {
            float4 z0 = *(const float4*)(zq);
            float4 z1 = *(const float4*)(zq + 32);
            float4 z2 = *(const float4*)(zq + 64);
            float4 z3 = *(const float4*)(zq + 96);
            float4 z4 = *(const float4*)(zq + 4);
            float4 z5 = *(const float4*)(zq + 36);
            float4 z6 = *(const float4*)(zq + 68);
            float4 z7 = *(const float4*)(zq + 100);
            zq += 132;
            float acc0 = 0.f, acc1 = 0.f;
            FQ(z0, 0)  FQ(z1, 4)  FQ(z2, 8)  FQ(z3, 12)
            FQ(z4, 16) FQ(z5, 20) FQ(z6, 24) FQ(z7, 28)
            acc0 += __shfl_xor(acc0, 16); acc1 += __shfl_xor(acc1, 16);
            acc0 += __shfl_xor(acc0, 32); acc1 += __shfl_xor(acc1, 32);
            if (ks == 0) {
                float o0 = fmaxf(acc0 + b20, 0.f), o1 = fmaxf(acc1 + b21, 0.f);
                tbuf[fh][ebase + e2][fi] = fmaf(o0, w30, o1 * w31);
            }
        }
#undef FQ
        __syncthreads();
        {
            const int e = tid >> 3, p = tid & 7;
            float s = (tbuf[0][e][p] + tbuf[0][e][p + 8]) +
                      (tbuf[1][e][p] + tbuf[1][e][p + 8]);
            s += __shfl_xor(s, 1); s += __shfl_xor(s, 2); s += __shfl_xor(s, 4);
            if (p == 0 && cb + e < end) outp[cb + e] = s + bias3;
        }
        __syncthreads();
    }
}

extern "C" void kernel_launch(void* const* d_in, const int* in_sizes, int n_in,
                              void* d_out, int out_size, void* d_ws, size_t ws_size,
                              hipStream_t stream)
{
    const float* x     = (const float*)d_in[0];
    const float* eattr = (const float*)d_in[1];
    const float* etab  = (const float*)d_in[2];
    const float* lng   = (const float*)d_in[3];
    const float* lnb   = (const float*)d_in[4];
    const float* Win   = (const float*)d_in[5];
    const float* bin   = (const float*)d_in[6];
    const float* Wl    = (const float*)d_in[7];
    const float* bl    = (const float*)d_in[8];
    const float* Wr    = (const float*)d_in[9];
    const float* bng   = (const float*)d_in[10];
    const float* bnb   = (const float*)d_in[11];
    const float* We1   = (const float*)d_in[12];
    const float* be1   = (const float*)d_in[13];
    const float* We2   = (const float*)d_in[14];
    const float* be2   = (const float*)d_in[15];
    const float* We3   = (const float*)d_in[16];
    const float* be3   = (const float*)d_in[17];
    const int*   eidx  = (const int*)d_in[18];
    const int*   nidx  = (const int*)d_in[19];

    const int nn = in_sizes[0] / NIN;     // 100000
    const int ne = in_sizes[1] / EIN;     // 1600000
    const int* row = eidx;
    const int* col = eidx + ne;
    const float invn = 1.0f / nn;

    float* ws = (float*)d_ws;
    const size_t big = (size_t)nn * HID;
    float* h    = ws;                 // N*128
    float* bufB = ws + big;           // N*128  (initial; later B-projection)
    float* bufA = ws + 2 * big;       // N*128  (agg / gemm-out; later A-projection)
    float* tail = ws + 3 * big;

    const size_t need_csr = (3 * big + 3 * (size_t)nn + 1 + (size_t)ne + 512) * 4;
    const bool use_csr = (ws_size >= need_csr);

    if (use_csr) {
        int*   degi  = (int*)tail;                  // N
        int*   offs  = degi + nn;                   // N+1
        int*   cur   = offs + nn + 1;               // N
        int*   csr   = cur + nn;                    // E
        float* stats = (float*)(csr + ne);          // 256

        k_input<<<512, 256, 0, stream>>>(x, etab, nidx, lng, lnb, Win, bin, h, bufB,
                                         degi, cur, nn);
        k_deg<<<1024, 256, 0, stream>>>(col, degi, ne);
        k_scan<<<1, 1024, 0, stream>>>(degi, offs, nn);
        k_fill<<<1024, 256, 0, stream>>>(row, col, offs, cur, csr, ne);

        for (int i = 0; i < 3; i++) {
            k_agg<<<2048, 256, 0, stream>>>(h, offs, csr, bufA, stats, nn);
            k_gemm<<<256, 768, 0, stream>>>(bufA, nullptr, Wl + (size_t)i * HID * HID,
                                            h, Wr + (size_t)i * HID * HID, bl + i * HID,
                                            bufA, stats, nn);
            if (i < 2) {
                k_update<<<1024, 256, 0, stream>>>(bufA, stats, bng + i * HID, bnb + i * HID,
                                                   h, bufB, i & 1, nn * HID / 4, invn);
            } else {
                k_proj<<<256, 768, 0, stream>>>(bufA, stats, bng + i * HID, bnb + i * HID,
                                                h, We1, We1 + HID * HID, be1,
                                                bufA, bufB, nn, invn);
            }
        }
    } else {
        float* deg   = tail;                        // N
        float* inv   = deg + nn;                    // N
        float* stats = inv + nn;                    // 256

        k_input<<<512, 256, 0, stream>>>(x, etab, nidx, lng, lnb, Win, bin, h, bufB,
                                         nullptr, nullptr, nn);
        hipMemsetAsync(deg, 0, (size_t)nn * 4, stream);
        k_degf<<<1024, 256, 0, stream>>>(col, deg, ne);
        k_invdeg<<<(nn + 255) / 256, 256, 0, stream>>>(deg, inv, nn);

        for (int i = 0; i < 3; i++) {
            hipMemsetAsync(bufA, 0, big * 4, stream);
            k_scatter<<<2048, 256, 0, stream>>>(h, row, col, bufA, stats, ne);
            k_gemm<<<256, 768, 0, stream>>>(bufA, inv, Wl + (size_t)i * HID * HID,
                                            h, Wr + (size_t)i * HID * HID, bl + i * HID,
                                            bufA, stats, nn);
            if (i < 2) {
                k_update<<<1024, 256, 0, stream>>>(bufA, stats, bng + i * HID, bnb + i * HID,
                                                   h, bufB, i & 1, nn * HID / 4, invn);
            } else {
                k_proj<<<256, 768, 0, stream>>>(bufA, stats, bng + i * HID, bnb + i * HID,
                                                h, We1, We1 + HID * HID, be1,
                                                bufA, bufB, nn, invn);
            }
        }
    }

    const int half = (ne / 2) & ~31;
    k_edge<<<1792, 256, 0, stream>>>(bufA, bufB, eattr, row, col,
                                     We1 + 2 * HID * HID, We2, be2, We3, be3,
                                     (float*)d_out, 0, half, ne);
    k_edge<<<1792, 256, 0, stream>>>(bufA, bufB, eattr, row, col,
                                     We1 + 2 * HID * HID, We2, be2, We3, be3,
                                     (float*)d_out, half, ne, ne);
}